// Round 6
// baseline (357.681 us; speedup 1.0000x reference)
//
#include <hip/hip_runtime.h>
#include <hip/hip_bf16.h>
#include <stdint.h>
#include <math.h>

#define EPSV 1e-7f
#define B_   8
#define CIN  512
#define COUT 512
#define HH   64
#define WW   64
#define SS   512
#define HP   66
#define WP   66
#define NP   (HH*WW)   // 4096 spatial

typedef __attribute__((ext_vector_type(8)))  short bf16x8;
typedef __attribute__((ext_vector_type(4)))  float f32x4;

#define MODSCALE 0.014731391274719739f   // 1/sqrt(4608)

// ------------- kernel 1: m[b][ci] = scale * (style @ mod_w^T + mod_b) --------
__global__ __launch_bounds__(256) void k_mod(const float* __restrict__ style,
                                             const float* __restrict__ mod_w,
                                             const float* __restrict__ mod_b,
                                             float* __restrict__ m_out) {
    int tid = threadIdx.x;
    int id = blockIdx.x * 64 + (tid >> 2);     // 64 blocks x 64 outputs
    int b = id >> 9, ci = id & 511, q = tid & 3;
    const float4* st = (const float4*)(style + (size_t)b * SS);
    const float4* mw = (const float4*)(mod_w + (size_t)ci * SS);
    float acc = 0.f;
    #pragma unroll
    for (int j = 0; j < 32; ++j) {
        float4 s4 = st[q * 32 + j];
        float4 w4 = mw[q * 32 + j];
        acc += s4.x * w4.x + s4.y * w4.y + s4.z * w4.z + s4.w * w4.w;
    }
    acc += __shfl_xor(acc, 1);
    acc += __shfl_xor(acc, 2);
    if (q == 0) m_out[id] = MODSCALE * (acc + mod_b[ci]);
}

// -- kernel 2: weight f32 -> wt[t][co][ci] bf16, + dfac[b][co] (fused demod) --
__global__ __launch_bounds__(256) void k_wprep(const float* __restrict__ weight,
                                               const float* __restrict__ m_buf,
                                               __hip_bfloat16* __restrict__ wt,
                                               float* __restrict__ dfac) {
    const int co  = blockIdx.x;              // 512 blocks
    const int tid = threadIdx.x;
    const int lane = tid & 63, wid = tid >> 6;
    __shared__ float wrow[4608];
    __shared__ float red[4][8];
    const float2* wsrc = (const float2*)(weight + (size_t)co * 4608);
    #pragma unroll
    for (int i = 0; i < 9; ++i)
        *(float2*)&wrow[(i * 256 + tid) * 2] = wsrc[i * 256 + tid];
    __syncthreads();
    float w0[9], w1[9], sq0 = 0.f, sq1 = 0.f;
    #pragma unroll
    for (int t = 0; t < 9; ++t) {
        w0[t] = wrow[tid * 9 + t];
        w1[t] = wrow[(tid + 256) * 9 + t];
        sq0 += w0[t] * w0[t];
        sq1 += w1[t] * w1[t];
    }
    float part[8];
    #pragma unroll
    for (int b = 0; b < 8; ++b) {
        float m0 = m_buf[b * CIN + tid];
        float m1 = m_buf[b * CIN + tid + 256];
        part[b] = sq0 * m0 * m0 + sq1 * m1 * m1;
    }
    #pragma unroll
    for (int b = 0; b < 8; ++b) {
        float v = part[b];
        #pragma unroll
        for (int off = 32; off > 0; off >>= 1) v += __shfl_xor(v, off);
        part[b] = v;
    }
    if (lane == 0) {
        #pragma unroll
        for (int b = 0; b < 8; ++b) red[wid][b] = part[b];
    }
    #pragma unroll
    for (int t = 0; t < 9; ++t) {
        size_t base = (size_t)t * COUT * CIN + (size_t)co * CIN;
        wt[base + tid]       = __float2bfloat16(w0[t]);
        wt[base + tid + 256] = __float2bfloat16(w1[t]);
    }
    __syncthreads();
    if (tid < 8)
        dfac[tid * COUT + co] =
            sqrtf(red[0][tid] + red[1][tid] + red[2][tid] + red[3][tid] + EPSV);
}

// ---- kernel 3: x[b][ci][h][w] f32 -> xpadM[b][h+1][w+1][ci] = bf16(x*m) -----
__global__ __launch_bounds__(256) void k_xpad(const float* __restrict__ x,
                                              const float* __restrict__ m_buf,
                                              __hip_bfloat16* __restrict__ xpad) {
    const int b = blockIdx.x >> 6;
    const int h = blockIdx.x & 63;
    const int tid = threadIdx.x;
    __shared__ float tile[64][65];
    for (int ci0 = 0; ci0 < CIN; ci0 += 64) {
        #pragma unroll
        for (int it = 0; it < 4; ++it) {
            int idx = it * 256 + tid;
            int w4 = idx & 15, cil = idx >> 4;
            float4 v = *(const float4*)&x[(((size_t)b * CIN + ci0 + cil) * HH + h) * WW + 4 * w4];
            tile[cil][4 * w4 + 0] = v.x; tile[cil][4 * w4 + 1] = v.y;
            tile[cil][4 * w4 + 2] = v.z; tile[cil][4 * w4 + 3] = v.w;
        }
        __syncthreads();
        #pragma unroll
        for (int it = 0; it < 4; ++it) {
            int idx = it * 256 + tid;
            int c4 = idx & 15, w = idx >> 4;
            float4 mv = *(const float4*)&m_buf[b * CIN + ci0 + 4 * c4];
            __hip_bfloat16 t0 = __float2bfloat16(tile[4 * c4 + 0][w] * mv.x);
            __hip_bfloat16 t1 = __float2bfloat16(tile[4 * c4 + 1][w] * mv.y);
            __hip_bfloat16 t2 = __float2bfloat16(tile[4 * c4 + 2][w] * mv.z);
            __hip_bfloat16 t3 = __float2bfloat16(tile[4 * c4 + 3][w] * mv.w);
            ushort4 pk = make_ushort4(*(unsigned short*)&t0, *(unsigned short*)&t1,
                                      *(unsigned short*)&t2, *(unsigned short*)&t3);
            *(ushort4*)&xpad[(((size_t)b * HP + h + 1) * WP + (w + 1)) * CIN + ci0 + 4 * c4] = pk;
        }
        __syncthreads();
    }
    // zero borders
    const size_t base = (size_t)b * HP * WP * CIN;
    const ushort4 z4 = make_ushort4(0, 0, 0, 0);
    {
        int wp = (tid < 128) ? 0 : 65;
        int e  = (tid & 127) * 4;
        *(ushort4*)&xpad[base + ((size_t)(h + 1) * WP + wp) * CIN + e] = z4;
    }
    if (h == 0 || h == 63) {
        int hp = (h == 0) ? 0 : 65;
        for (int i = tid; i < (HP * CIN) / 4; i += 256)
            *(ushort4*)&xpad[base + (size_t)hp * WP * CIN + (size_t)i * 4] = z4;
    }
}

// ------- kernel 4: conv; B staged in LDS, A fragments direct from global -----
// acc[co,p] = sum over t(9),ci(512) of wt[t][co][ci] * xpadM[..][ci]
// out = acc * dfac[b][co].  144 K-tiles BK=32; 4 B-buffers; publish mid-tile.

#define MM(A,B,C) __builtin_amdgcn_mfma_f32_16x16x32_bf16(A,B,C,0,0,0)

#define GLDS(GP, LOFF) __builtin_amdgcn_global_load_lds( \
    (const __attribute__((address_space(1))) void*)(GP), \
    (__attribute__((address_space(3))) void*)(smem + (LOFF)), 16, 0, 0)

#define LDB(SB, N) (*(const bf16x8*)(bLds + ((SB)*16384 + (N)*1024)))

// A fragment straight from global: tap = KT>>4, ci-chunk = (KT&15)*32
#define AG(KT, M) (*(const bf16x8*)(wt + (size_t)((KT) >> 4) * (COUT * CIN) \
                                    + (((KT) & 15) * 32) + aBase + (M) * (16 * CIN)))

#define STAGE_B(KT, SB) { const int t3_ = (KT) >> 4, ci3_ = ((KT) & 15) * 32;   \
    const int bO_ = ((t3_ / 3) * WP + (t3_ % 3)) * CIN + ci3_;                  \
    GLDS(xpad + bO_ + gB0, (SB) * 16384 + ldsd);                                \
    GLDS(xpad + bO_ + gB1, (SB) * 16384 + 8192 + ldsd); }

#define BARRIER asm volatile("s_barrier" ::: "memory")
#define VM6 asm volatile("s_waitcnt vmcnt(6)" ::: "memory");
#define VM4 asm volatile("s_waitcnt vmcnt(4)" ::: "memory");

#define CCOL(N, BV) acc[0][N]=MM(ca0,BV,acc[0][N]); acc[1][N]=MM(ca1,BV,acc[1][N]); \
                    acc[2][N]=MM(ca2,BV,acc[2][N]); acc[3][N]=MM(ca3,BV,acc[3][N]);
#define XCOL(N, BV) acc[4][N]=MM(x4_,BV,acc[4][N]); acc[5][N]=MM(x5_,BV,acc[5][N]); \
                    acc[6][N]=MM(x6_,BV,acc[6][N]); acc[7][N]=MM(x7_,BV,acc[7][N]);

// Per tile KK (buffer SB=KK&3): arrive with ca0-3 (A low, global, issued last
// tile), cb0,cb1 in regs.  x4-7 (A high) loaded at top, used after publish.
#define KTILE4(KK, SB, DOSTAGE, DONEXT) {                                       \
    cb2 = LDB(SB, 2); cb3 = LDB(SB, 3);                                         \
    bf16x8 x4_ = AG(KK,4), x5_ = AG(KK,5), x6_ = AG(KK,6), x7_ = AG(KK,7);      \
    if (DOSTAGE) { STAGE_B((KK)+3, ((SB)+3)&3); }                               \
    __builtin_amdgcn_s_setprio(1);                                              \
    CCOL(0, cb0) CCOL(1, cb1) CCOL(2, cb2) CCOL(3, cb3)                         \
    __builtin_amdgcn_s_setprio(0);                                              \
    __builtin_amdgcn_sched_barrier(0);                                          \
    VM6                                                                         \
    BARRIER;                                                                    \
    __builtin_amdgcn_sched_barrier(0);                                          \
    if (DONEXT) { const int nsb_ = ((SB)+1)&3;                                  \
        ca0 = AG((KK)+1,0); ca1 = AG((KK)+1,1);                                 \
        ca2 = AG((KK)+1,2); ca3 = AG((KK)+1,3);                                 \
        nb0_ = LDB(nsb_,0); nb1_ = LDB(nsb_,1);                                 \
    }                                                                           \
    __builtin_amdgcn_s_setprio(1);                                              \
    XCOL(0, cb0) XCOL(1, cb1) XCOL(2, cb2) XCOL(3, cb3)                         \
    __builtin_amdgcn_s_setprio(0);                                              \
    cb0 = nb0_; cb1 = nb1_;                                                     \
}

__global__ __launch_bounds__(512, 2) void k_conv(const __hip_bfloat16* __restrict__ wt,
                                                 const __hip_bfloat16* __restrict__ xpad,
                                                 const float* __restrict__ dfac,
                                                 float* __restrict__ out) {
    __shared__ __align__(16) char smem[65536];   // B only: 4 bufs x 16 KB

    const int tid  = threadIdx.x;
    const int lane = tid & 63;
    const int wid  = tid >> 6;           // 8 waves
    const int wr   = wid >> 2;           // 0..1  (M: 128 rows each)
    const int wc   = wid & 3;            // 0..3  (N: 64 cols each)
    const int frow = lane & 15;
    const int fk   = lane >> 4;          // 0..3 (k-chunk of 8 bf16)

    // XCD-major decode: bid%8 = batch
    const int bid = blockIdx.x;
    const int bb  = bid & 7;
    const int pt  = (bid >> 3) & 15;
    const int ct  = bid >> 7;
    const int co0 = ct * 256;
    const int p0  = pt * 256;

    // B ds_read base: row*64B + swizzled chunk; swz(row)=(row>>1)&3=(frow>>1)&3
    const int xr = (fk ^ ((frow >> 1) & 3)) * 16;
    const char* bLds = smem + (wc * 4096 + frow * 64 + xr);

    // A global fragment base (per-lane): row co0+wr*128+frow, k-chunk fk
    const int aBase = (co0 + wr * 128 + frow) * CIN + fk * 8;

    // B staging: 16 rows x 64B per wave-instr, linear LDS; source pre-swizzled
    const int ldsd = tid * 16;
    const int srow = wid * 16 + (lane >> 2);
    const int cg   = ((lane & 3) ^ ((lane >> 3) & 3)) * 8;
    const int pp0  = p0 + srow;
    const int pp1  = p0 + 128 + srow;
    const int gB0  = ((bb * HP + (pp0 >> 6)) * WP + (pp0 & 63)) * CIN + cg;
    const int gB1  = ((bb * HP + (pp1 >> 6)) * WP + (pp1 & 63)) * CIN + cg;

    f32x4 acc[8][4];
    #pragma unroll
    for (int m = 0; m < 8; ++m)
        #pragma unroll
        for (int n = 0; n < 4; ++n)
            acc[m][n] = (f32x4){0.f, 0.f, 0.f, 0.f};

    bf16x8 ca0, ca1, ca2, ca3, cb0, cb1, cb2, cb3, nb0_, nb1_;

    // prologue: stage B-tiles 0,1,2 into bufs 0,1,2
    STAGE_B(0, 0)
    STAGE_B(1, 1)
    STAGE_B(2, 2)
    VM4;       // B-tile 0 landed
    BARRIER;
    cb0 = LDB(0, 0); cb1 = LDB(0, 1);
    ca0 = AG(0, 0); ca1 = AG(0, 1); ca2 = AG(0, 2); ca3 = AG(0, 3);

    for (int k4 = 0; k4 < 140; k4 += 4) {
        KTILE4(k4 + 0, 0, 1, 1)
        KTILE4(k4 + 1, 1, 1, 1)
        KTILE4(k4 + 2, 2, 1, 1)
        KTILE4(k4 + 3, 3, 1, 1)
    }
    KTILE4(140, 0, 1, 1)     // stages B-tile 143
    KTILE4(141, 1, 0, 1)
    KTILE4(142, 2, 0, 1)
    KTILE4(143, 3, 0, 0)

    // epilogue: C/D mapping col(lane&15)=p, row=(lane>>4)*4+j = co; * dfac
    const float* dfb = dfac + bb * COUT;
    #pragma unroll
    for (int m = 0; m < 8; ++m) {
        int co = co0 + wr * 128 + m * 16 + fk * 4;
        float d0 = dfb[co + 0], d1 = dfb[co + 1], d2 = dfb[co + 2], d3 = dfb[co + 3];
        #pragma unroll
        for (int n = 0; n < 4; ++n) {
            int p = p0 + wc * 64 + n * 16 + frow;
            size_t ob = ((size_t)(bb * COUT + co)) * NP + p;
            out[ob]          = acc[m][n][0] * d0;
            out[ob + NP]     = acc[m][n][1] * d1;
            out[ob + 2 * NP] = acc[m][n][2] * d2;
            out[ob + 3 * NP] = acc[m][n][3] * d3;
        }
    }
}

// -----------------------------------------------------------------------------
extern "C" void kernel_launch(void* const* d_in, const int* in_sizes, int n_in,
                              void* d_out, int out_size, void* d_ws, size_t ws_size,
                              hipStream_t stream) {
    const float* x      = (const float*)d_in[0];
    const float* style  = (const float*)d_in[1];
    const float* weight = (const float*)d_in[2];
    const float* mod_w  = (const float*)d_in[3];
    const float* mod_b  = (const float*)d_in[4];
    float* out = (float*)d_out;

    char* ws = (char*)d_ws;
    const size_t M_OFF    = 0;                        // 8*512*4   = 16 KB
    const size_t DFAC_OFF = 16384;                    // 8*512*4   = 16 KB
    const size_t WT_OFF   = 32768;                    // 9*512*512*2 = 4.5 MB
    const size_t XPAD_OFF = WT_OFF + (size_t)9 * COUT * CIN * 2;

    float*          m_buf = (float*)(ws + M_OFF);
    float*          dfac  = (float*)(ws + DFAC_OFF);
    __hip_bfloat16* wt    = (__hip_bfloat16*)(ws + WT_OFF);
    __hip_bfloat16* xpad  = (__hip_bfloat16*)(ws + XPAD_OFF);

    k_mod<<<64, 256, 0, stream>>>(style, mod_w, mod_b, m_buf);
    k_wprep<<<512, 256, 0, stream>>>(weight, m_buf, wt, dfac);
    k_xpad<<<B_ * HH, 256, 0, stream>>>(x, m_buf, xpad);

    k_conv<<<256, 512, 0, stream>>>(wt, xpad, dfac, out);
}

// Round 7
// 153.410 us; speedup vs baseline: 2.3315x; 2.3315x over previous
//
#include <hip/hip_runtime.h>
#include <hip/hip_bf16.h>
#include <stdint.h>
#include <math.h>

#define EPSV 1e-7f
#define B_   8
#define CIN  512
#define COUT 512
#define HH   64
#define WW   64
#define SS   512
#define HP   66
#define WP   66
#define NP   (HH*WW)   // 4096 spatial

typedef __attribute__((ext_vector_type(8)))  short bf16x8;
typedef __attribute__((ext_vector_type(4)))  float f32x4;

#define MODSCALE 0.014731391274719739f   // 1/sqrt(4608)

// ------------- kernel 1: m[b][ci] = scale * (style @ mod_w^T + mod_b) --------
__global__ __launch_bounds__(256) void k_mod(const float* __restrict__ style,
                                             const float* __restrict__ mod_w,
                                             const float* __restrict__ mod_b,
                                             float* __restrict__ m_out) {
    int tid = threadIdx.x;
    int id = blockIdx.x * 64 + (tid >> 2);     // 64 blocks x 64 outputs
    int b = id >> 9, ci = id & 511, q = tid & 3;
    const float4* st = (const float4*)(style + (size_t)b * SS);
    const float4* mw = (const float4*)(mod_w + (size_t)ci * SS);
    float acc = 0.f;
    #pragma unroll
    for (int j = 0; j < 32; ++j) {
        float4 s4 = st[q * 32 + j];
        float4 w4 = mw[q * 32 + j];
        acc += s4.x * w4.x + s4.y * w4.y + s4.z * w4.z + s4.w * w4.w;
    }
    acc += __shfl_xor(acc, 1);
    acc += __shfl_xor(acc, 2);
    if (q == 0) m_out[id] = MODSCALE * (acc + mod_b[ci]);
}

// -- kernel 2: weight f32 -> wt[t][co][ci] bf16, + dfac[b][co] (fused demod) --
__global__ __launch_bounds__(256) void k_wprep(const float* __restrict__ weight,
                                               const float* __restrict__ m_buf,
                                               __hip_bfloat16* __restrict__ wt,
                                               float* __restrict__ dfac) {
    const int co  = blockIdx.x;              // 512 blocks
    const int tid = threadIdx.x;
    const int lane = tid & 63, wid = tid >> 6;
    __shared__ float wrow[4608];
    __shared__ float red[4][8];
    const float2* wsrc = (const float2*)(weight + (size_t)co * 4608);
    #pragma unroll
    for (int i = 0; i < 9; ++i)
        *(float2*)&wrow[(i * 256 + tid) * 2] = wsrc[i * 256 + tid];
    __syncthreads();
    float w0[9], w1[9], sq0 = 0.f, sq1 = 0.f;
    #pragma unroll
    for (int t = 0; t < 9; ++t) {
        w0[t] = wrow[tid * 9 + t];
        w1[t] = wrow[(tid + 256) * 9 + t];
        sq0 += w0[t] * w0[t];
        sq1 += w1[t] * w1[t];
    }
    float part[8];
    #pragma unroll
    for (int b = 0; b < 8; ++b) {
        float m0 = m_buf[b * CIN + tid];
        float m1 = m_buf[b * CIN + tid + 256];
        part[b] = sq0 * m0 * m0 + sq1 * m1 * m1;
    }
    #pragma unroll
    for (int b = 0; b < 8; ++b) {
        float v = part[b];
        #pragma unroll
        for (int off = 32; off > 0; off >>= 1) v += __shfl_xor(v, off);
        part[b] = v;
    }
    if (lane == 0) {
        #pragma unroll
        for (int b = 0; b < 8; ++b) red[wid][b] = part[b];
    }
    #pragma unroll
    for (int t = 0; t < 9; ++t) {
        size_t base = (size_t)t * COUT * CIN + (size_t)co * CIN;
        wt[base + tid]       = __float2bfloat16(w0[t]);
        wt[base + tid + 256] = __float2bfloat16(w1[t]);
    }
    __syncthreads();
    if (tid < 8)
        dfac[tid * COUT + co] =
            sqrtf(red[0][tid] + red[1][tid] + red[2][tid] + red[3][tid] + EPSV);
}

// ---- kernel 3: x[b][ci][h][w] f32 -> xpadM[b][h+1][w+1][ci] = bf16(x*m) -----
// 2048 blocks = (b, h, ci-quarter); swizzled LDS transpose; 16B stores
__global__ __launch_bounds__(256) void k_xpad(const float* __restrict__ x,
                                              const float* __restrict__ m_buf,
                                              __hip_bfloat16* __restrict__ xpad) {
    const int bidx = blockIdx.x;
    const int q = bidx & 3;            // ci quarter (128 ci)
    const int h = (bidx >> 2) & 63;
    const int b = bidx >> 8;
    const int tid = threadIdx.x;
    const int ci0 = q * 128;
    __shared__ float tile[128][65];

    // load: x[b][ci0+cl][h][0..63], physical col swizzle w4' = w4 ^ (cl>>3)
    #pragma unroll
    for (int it = 0; it < 8; ++it) {
        int idx = it * 256 + tid;
        int w4 = idx & 15, cl = idx >> 4;
        float4 v = *(const float4*)&x[(((size_t)b * CIN + ci0 + cl) * HH + h) * WW + 4 * w4];
        float* dst = &tile[cl][4 * (w4 ^ (cl >> 3))];
        dst[0] = v.x; dst[1] = v.y; dst[2] = v.z; dst[3] = v.w;
    }
    __syncthreads();

    // write: xpad[...][ci0 + 8cg + j] = bf16(tile[8cg+j][w] * m); short8 stores
    #pragma unroll
    for (int it = 0; it < 4; ++it) {
        int idx = it * 256 + tid;
        int cg = idx & 15, w = idx >> 4;
        int pcol = 4 * ((w >> 2) ^ cg) + (w & 3);   // row 8cg+j -> row>>3 = cg
        bf16x8 pk;
        #pragma unroll
        for (int j = 0; j < 8; ++j) {
            float mv = m_buf[b * CIN + ci0 + 8 * cg + j];
            __hip_bfloat16 t = __float2bfloat16(tile[8 * cg + j][pcol] * mv);
            pk[j] = *(short*)&t;
        }
        *(bf16x8*)&xpad[(((size_t)b * HP + h + 1) * WP + (w + 1)) * CIN + ci0 + 8 * cg] = pk;
    }

    // zero borders
    const size_t base = (size_t)b * HP * WP * CIN;
    const bf16x8 z8 = (bf16x8)(short)0;
    if (tid < 32) {    // columns wp=0 and wp=65 of row hp=h+1, own ci-quarter
        int wp = (tid >> 4) ? 65 : 0;
        int grp = tid & 15;
        *(bf16x8*)&xpad[base + ((size_t)(h + 1) * WP + wp) * CIN + ci0 + 8 * grp] = z8;
    }
    if (h == 0 || h == 63) {   // rows hp=0 / hp=65, own ci-quarter
        int hp = (h == 0) ? 0 : 65;
        for (int i = tid; i < 66 * 16; i += 256) {
            int wp = i >> 4, grp = i & 15;
            *(bf16x8*)&xpad[base + ((size_t)hp * WP + wp) * CIN + ci0 + 8 * grp] = z8;
        }
    }
}

// ------- kernel 4: conv, round-5 16x16x32 schedule, all-operands-resident ----
// acc[co,p] = sum over t(9),ci(512) of wt[t][co][ci] * xpadM[..][ci]
// out = acc * dfac[b][co].  144 K-tiles BK=32; 4 LDS bufs; mid-tile publish.

#define MM(A,B,C) __builtin_amdgcn_mfma_f32_16x16x32_bf16(A,B,C,0,0,0)

#define GLDS(GP, LOFF) __builtin_amdgcn_global_load_lds( \
    (const __attribute__((address_space(1))) void*)(GP), \
    (__attribute__((address_space(3))) void*)(smem + (LOFF)), 16, 0, 0)

#define LDA(SB, M) (*(const bf16x8*)(aLds + ((SB)*16384 + (M)*1024)))
#define LDB(SB, N) (*(const bf16x8*)(bLds + ((SB)*16384 + (N)*1024)))

#define STAGE_A(KT, SB) { const int t3_ = (KT) >> 4, ci3_ = ((KT) & 15) * 32;   \
    const size_t aB_ = (size_t)t3_ * (COUT * CIN) + ci3_;                       \
    GLDS(wt + aB_ + gA0, (SB) * 16384 + ldsd);                                  \
    GLDS(wt + aB_ + gA1, (SB) * 16384 + 8192 + ldsd); }

#define STAGE_B(KT, SB) { const int t3_ = (KT) >> 4, ci3_ = ((KT) & 15) * 32;   \
    const int bO_ = ((t3_ / 3) * WP + (t3_ % 3)) * CIN + ci3_;                  \
    GLDS(xpad + bO_ + gB0, 65536 + (SB) * 16384 + ldsd);                        \
    GLDS(xpad + bO_ + gB1, 65536 + (SB) * 16384 + 8192 + ldsd); }

#define BARRIER asm volatile("s_barrier" ::: "memory")
#define VM8 asm volatile("s_waitcnt vmcnt(8)" ::: "memory");
#define VM4 asm volatile("s_waitcnt vmcnt(4)" ::: "memory");
#define VM0 asm volatile("s_waitcnt vmcnt(0)" ::: "memory");
#define VMNONE

#define CCOL(N, BV) acc[0][N]=MM(ca0,BV,acc[0][N]); acc[1][N]=MM(ca1,BV,acc[1][N]); \
                    acc[2][N]=MM(ca2,BV,acc[2][N]); acc[3][N]=MM(ca3,BV,acc[3][N]);
#define XCOL(N, BV) acc[4][N]=MM(x4_,BV,acc[4][N]); acc[5][N]=MM(x5_,BV,acc[5][N]); \
                    acc[6][N]=MM(x6_,BV,acc[6][N]); acc[7][N]=MM(x7_,BV,acc[7][N]);

// Per tile KK (buffer SB=KK&3): arrive with ca0-3 and cb0-3 resident.
// top: read A-hi(x4-7) of cur tile; stage tile KK+3.
// cluster1 -> publish KK+1 (vmcnt + barrier) -> read next tile's ca0-3, nb0-3
// (overlapping cluster2's MFMAs) -> cluster2 -> rotate nb->cb.
#define KTILE3(KK, SB, DOSTAGE, WAITER, DONEXT) {                               \
    bf16x8 x4_ = LDA(SB,4), x5_ = LDA(SB,5), x6_ = LDA(SB,6), x7_ = LDA(SB,7);  \
    if (DOSTAGE) { STAGE_A((KK)+3, ((SB)+3)&3); STAGE_B((KK)+3, ((SB)+3)&3); }  \
    __builtin_amdgcn_s_setprio(1);                                              \
    CCOL(0, cb0) CCOL(1, cb1) CCOL(2, cb2) CCOL(3, cb3)                         \
    __builtin_amdgcn_s_setprio(0);                                              \
    __builtin_amdgcn_sched_barrier(0);                                          \
    WAITER                                                                      \
    BARRIER;                                                                    \
    __builtin_amdgcn_sched_barrier(0);                                          \
    if (DONEXT) { const int nsb_ = ((SB)+1)&3;                                  \
        ca0 = LDA(nsb_,0); ca1 = LDA(nsb_,1);                                   \
        ca2 = LDA(nsb_,2); ca3 = LDA(nsb_,3);                                   \
        nb0_ = LDB(nsb_,0); nb1_ = LDB(nsb_,1);                                 \
        nb2_ = LDB(nsb_,2); nb3_ = LDB(nsb_,3);                                 \
    }                                                                           \
    __builtin_amdgcn_s_setprio(1);                                              \
    XCOL(0, cb0) XCOL(1, cb1) XCOL(2, cb2) XCOL(3, cb3)                         \
    __builtin_amdgcn_s_setprio(0);                                              \
    cb0 = nb0_; cb1 = nb1_; cb2 = nb2_; cb3 = nb3_;                             \
}

__global__ __launch_bounds__(512, 2) void k_conv(const __hip_bfloat16* __restrict__ wt,
                                                 const __hip_bfloat16* __restrict__ xpad,
                                                 const float* __restrict__ dfac,
                                                 float* __restrict__ out) {
    __shared__ __align__(16) char smem[131072];

    const int tid  = threadIdx.x;
    const int lane = tid & 63;
    const int wid  = tid >> 6;           // 8 waves
    const int wr   = wid >> 2;           // 0..1  (M: 128 rows each)
    const int wc   = wid & 3;            // 0..3  (N: 64 cols each)
    const int frow = lane & 15;
    const int fk   = lane >> 4;          // 0..3 (k-chunk of 8 bf16)

    // XCD-major decode: bid%8 = batch
    const int bid = blockIdx.x;
    const int bb  = bid & 7;
    const int pt  = (bid >> 3) & 15;
    const int ct  = bid >> 7;
    const int co0 = ct * 256;
    const int p0  = pt * 256;

    // ds_read bases: row*64B + swizzled chunk; swz(row) = (row>>1)&3 = (frow>>1)&3
    const int xr = (fk ^ ((frow >> 1) & 3)) * 16;
    const char* aLds = smem + (wr * 8192 + frow * 64 + xr);
    const char* bLds = smem + 65536 + (wc * 4096 + frow * 64 + xr);

    // staging: 16 rows x 64B per wave-instr, linear LDS; global source pre-swizzled
    const int ldsd = wid * 1024 + lane * 16;
    const int srow = wid * 16 + (lane >> 2);
    const int cg   = ((lane & 3) ^ ((lane >> 3) & 3)) * 8;
    const int gA0  = (co0 + srow) * CIN + cg;
    const int gA1  = (co0 + 128 + srow) * CIN + cg;
    const int pp0  = p0 + srow;
    const int pp1  = p0 + 128 + srow;
    const int gB0  = ((bb * HP + (pp0 >> 6)) * WP + (pp0 & 63)) * CIN + cg;
    const int gB1  = ((bb * HP + (pp1 >> 6)) * WP + (pp1 & 63)) * CIN + cg;

    f32x4 acc[8][4];
    #pragma unroll
    for (int m = 0; m < 8; ++m)
        #pragma unroll
        for (int n = 0; n < 4; ++n)
            acc[m][n] = (f32x4){0.f, 0.f, 0.f, 0.f};

    bf16x8 ca0, ca1, ca2, ca3, cb0, cb1, cb2, cb3, nb0_, nb1_, nb2_, nb3_;

    // prologue: stage K-tiles 0,1,2 into bufs 0,1,2
    STAGE_A(0, 0) STAGE_B(0, 0)
    STAGE_A(1, 1) STAGE_B(1, 1)
    STAGE_A(2, 2) STAGE_B(2, 2)
    VM8;       // tile 0 landed
    BARRIER;
    ca0 = LDA(0, 0); ca1 = LDA(0, 1); ca2 = LDA(0, 2); ca3 = LDA(0, 3);
    cb0 = LDB(0, 0); cb1 = LDB(0, 1); cb2 = LDB(0, 2); cb3 = LDB(0, 3);

    for (int k4 = 0; k4 < 140; k4 += 4) {
        KTILE3(k4 + 0, 0, 1, VM8, 1)
        KTILE3(k4 + 1, 1, 1, VM8, 1)
        KTILE3(k4 + 2, 2, 1, VM8, 1)
        KTILE3(k4 + 3, 3, 1, VM8, 1)
    }
    KTILE3(140, 0, 1, VM8, 1)     // stages tile 143; publishes 141
    KTILE3(141, 1, 0, VM4, 1)     // publishes 142
    KTILE3(142, 2, 0, VM0, 1)     // publishes 143
    KTILE3(143, 3, 0, VMNONE, 0)

    // epilogue: C/D mapping col(lane&15)=p, row=(lane>>4)*4+j = co; * dfac
    const float* dfb = dfac + bb * COUT;
    #pragma unroll
    for (int m = 0; m < 8; ++m) {
        int co = co0 + wr * 128 + m * 16 + fk * 4;
        float d0 = dfb[co + 0], d1 = dfb[co + 1], d2 = dfb[co + 2], d3 = dfb[co + 3];
        #pragma unroll
        for (int n = 0; n < 4; ++n) {
            int p = p0 + wc * 64 + n * 16 + frow;
            size_t ob = ((size_t)(bb * COUT + co)) * NP + p;
            out[ob]          = acc[m][n][0] * d0;
            out[ob + NP]     = acc[m][n][1] * d1;
            out[ob + 2 * NP] = acc[m][n][2] * d2;
            out[ob + 3 * NP] = acc[m][n][3] * d3;
        }
    }
}

// -----------------------------------------------------------------------------
extern "C" void kernel_launch(void* const* d_in, const int* in_sizes, int n_in,
                              void* d_out, int out_size, void* d_ws, size_t ws_size,
                              hipStream_t stream) {
    const float* x      = (const float*)d_in[0];
    const float* style  = (const float*)d_in[1];
    const float* weight = (const float*)d_in[2];
    const float* mod_w  = (const float*)d_in[3];
    const float* mod_b  = (const float*)d_in[4];
    float* out = (float*)d_out;

    char* ws = (char*)d_ws;
    const size_t M_OFF    = 0;                        // 8*512*4   = 16 KB
    const size_t DFAC_OFF = 16384;                    // 8*512*4   = 16 KB
    const size_t WT_OFF   = 32768;                    // 9*512*512*2 = 4.5 MB
    const size_t XPAD_OFF = WT_OFF + (size_t)9 * COUT * CIN * 2;

    float*          m_buf = (float*)(ws + M_OFF);
    float*          dfac  = (float*)(ws + DFAC_OFF);
    __hip_bfloat16* wt    = (__hip_bfloat16*)(ws + WT_OFF);
    __hip_bfloat16* xpad  = (__hip_bfloat16*)(ws + XPAD_OFF);

    k_mod<<<64, 256, 0, stream>>>(style, mod_w, mod_b, m_buf);
    k_wprep<<<512, 256, 0, stream>>>(weight, m_buf, wt, dfac);
    k_xpad<<<2048, 256, 0, stream>>>(x, m_buf, xpad);

    k_conv<<<256, 512, 0, stream>>>(wt, xpad, dfac, out);
}

// Round 8
// 150.394 us; speedup vs baseline: 2.3783x; 1.0201x over previous
//
#include <hip/hip_runtime.h>
#include <hip/hip_bf16.h>
#include <stdint.h>
#include <math.h>

#define EPSV 1e-7f
#define B_   8
#define CIN  512
#define COUT 512
#define HH   64
#define WW   64
#define SS   512
#define HP   66
#define WP   66
#define NP   (HH*WW)   // 4096 spatial

typedef __attribute__((ext_vector_type(8)))  short bf16x8;
typedef __attribute__((ext_vector_type(4)))  float f32x4;

#define MODSCALE 0.014731391274719739f   // 1/sqrt(4608)

// ------------- kernel 1: m[b][ci] = scale * (style @ mod_w^T + mod_b) --------
__global__ __launch_bounds__(256) void k_mod(const float* __restrict__ style,
                                             const float* __restrict__ mod_w,
                                             const float* __restrict__ mod_b,
                                             float* __restrict__ m_out) {
    int tid = threadIdx.x;
    int id = blockIdx.x * 64 + (tid >> 2);     // 64 blocks x 64 outputs
    int b = id >> 9, ci = id & 511, q = tid & 3;
    const float4* st = (const float4*)(style + (size_t)b * SS);
    const float4* mw = (const float4*)(mod_w + (size_t)ci * SS);
    float acc = 0.f;
    #pragma unroll
    for (int j = 0; j < 32; ++j) {
        float4 s4 = st[q * 32 + j];
        float4 w4 = mw[q * 32 + j];
        acc += s4.x * w4.x + s4.y * w4.y + s4.z * w4.z + s4.w * w4.w;
    }
    acc += __shfl_xor(acc, 1);
    acc += __shfl_xor(acc, 2);
    if (q == 0) m_out[id] = MODSCALE * (acc + mod_b[ci]);
}

// ---- kernel 2 (fused role-split): blocks 0..2047 = xpad, 2048..2559 = wprep -
// xpad: x[b][ci][h][w] f32 -> xpadM[b][h+1][w+1][ci] = bf16(x*m), borders zeroed
// wprep: weight f32 -> wt[t][co][ci] bf16, + dfac[b][co] = sqrt(sum w^2 m^2 + eps)
__global__ __launch_bounds__(256) void k_prep(const float* __restrict__ x,
                                              const float* __restrict__ weight,
                                              const float* __restrict__ m_buf,
                                              __hip_bfloat16* __restrict__ xpad,
                                              __hip_bfloat16* __restrict__ wt,
                                              float* __restrict__ dfac) {
    __shared__ __align__(16) char pls[33280];   // max(128*65*4, 4608*4 + 128)
    const int bidx = blockIdx.x;
    const int tid = threadIdx.x;

    if (bidx < 2048) {
        // ---------------- xpad role ----------------
        const int q = bidx & 3;            // ci quarter (128 ci)
        const int h = (bidx >> 2) & 63;
        const int b = bidx >> 8;
        const int ci0 = q * 128;
        float (*tile)[65] = (float (*)[65])pls;

        // load: x[b][ci0+cl][h][0..63], physical col swizzle w4' = w4 ^ (cl>>3)
        #pragma unroll
        for (int it = 0; it < 8; ++it) {
            int idx = it * 256 + tid;
            int w4 = idx & 15, cl = idx >> 4;
            float4 v = *(const float4*)&x[(((size_t)b * CIN + ci0 + cl) * HH + h) * WW + 4 * w4];
            float* dst = &tile[cl][4 * (w4 ^ (cl >> 3))];
            dst[0] = v.x; dst[1] = v.y; dst[2] = v.z; dst[3] = v.w;
        }
        __syncthreads();

        // write: xpad[...][ci0 + 8cg + j] = bf16(tile[8cg+j][w] * m); short8 stores
        #pragma unroll
        for (int it = 0; it < 4; ++it) {
            int idx = it * 256 + tid;
            int cg = idx & 15, w = idx >> 4;
            int pcol = 4 * ((w >> 2) ^ cg) + (w & 3);   // row 8cg+j -> row>>3 = cg
            bf16x8 pk;
            #pragma unroll
            for (int j = 0; j < 8; ++j) {
                float mv = m_buf[b * CIN + ci0 + 8 * cg + j];
                __hip_bfloat16 t = __float2bfloat16(tile[8 * cg + j][pcol] * mv);
                pk[j] = *(short*)&t;
            }
            *(bf16x8*)&xpad[(((size_t)b * HP + h + 1) * WP + (w + 1)) * CIN + ci0 + 8 * cg] = pk;
        }

        // zero borders
        const size_t base = (size_t)b * HP * WP * CIN;
        const bf16x8 z8 = (bf16x8)(short)0;
        if (tid < 32) {    // columns wp=0 and wp=65 of row hp=h+1, own ci-quarter
            int wp = (tid >> 4) ? 65 : 0;
            int grp = tid & 15;
            *(bf16x8*)&xpad[base + ((size_t)(h + 1) * WP + wp) * CIN + ci0 + 8 * grp] = z8;
        }
        if (h == 0 || h == 63) {   // rows hp=0 / hp=65, own ci-quarter
            int hp = (h == 0) ? 0 : 65;
            for (int i = tid; i < 66 * 16; i += 256) {
                int wp = i >> 4, grp = i & 15;
                *(bf16x8*)&xpad[base + ((size_t)hp * WP + wp) * CIN + ci0 + 8 * grp] = z8;
            }
        }
    } else {
        // ---------------- wprep role ----------------
        const int co = bidx - 2048;              // 512 blocks
        const int lane = tid & 63, wid = tid >> 6;
        float* wrow = (float*)pls;                         // 4608 floats
        float (*red)[8] = (float (*)[8])(pls + 4608 * 4);  // [4][8]
        const float2* wsrc = (const float2*)(weight + (size_t)co * 4608);
        #pragma unroll
        for (int i = 0; i < 9; ++i)
            *(float2*)&wrow[(i * 256 + tid) * 2] = wsrc[i * 256 + tid];
        __syncthreads();
        float w0[9], w1[9], sq0 = 0.f, sq1 = 0.f;
        #pragma unroll
        for (int t = 0; t < 9; ++t) {
            w0[t] = wrow[tid * 9 + t];
            w1[t] = wrow[(tid + 256) * 9 + t];
            sq0 += w0[t] * w0[t];
            sq1 += w1[t] * w1[t];
        }
        float part[8];
        #pragma unroll
        for (int b = 0; b < 8; ++b) {
            float m0 = m_buf[b * CIN + tid];
            float m1 = m_buf[b * CIN + tid + 256];
            part[b] = sq0 * m0 * m0 + sq1 * m1 * m1;
        }
        #pragma unroll
        for (int b = 0; b < 8; ++b) {
            float v = part[b];
            #pragma unroll
            for (int off = 32; off > 0; off >>= 1) v += __shfl_xor(v, off);
            part[b] = v;
        }
        if (lane == 0) {
            #pragma unroll
            for (int b = 0; b < 8; ++b) red[wid][b] = part[b];
        }
        #pragma unroll
        for (int t = 0; t < 9; ++t) {
            size_t base = (size_t)t * COUT * CIN + (size_t)co * CIN;
            wt[base + tid]       = __float2bfloat16(w0[t]);
            wt[base + tid + 256] = __float2bfloat16(w1[t]);
        }
        __syncthreads();
        if (tid < 8)
            dfac[tid * COUT + co] =
                sqrtf(red[0][tid] + red[1][tid] + red[2][tid] + red[3][tid] + EPSV);
    }
}

// ------- kernel 3: conv, 16x16x32 pipelined-fragment schedule (round-7) ------
// acc[co,p] = sum over t(9),ci(512) of wt[t][co][ci] * xpadM[..][ci]
// out = acc * dfac[b][co].  144 K-tiles BK=32; 4 LDS bufs; mid-tile publish.

#define MM(A,B,C) __builtin_amdgcn_mfma_f32_16x16x32_bf16(A,B,C,0,0,0)

#define GLDS(GP, LOFF) __builtin_amdgcn_global_load_lds( \
    (const __attribute__((address_space(1))) void*)(GP), \
    (__attribute__((address_space(3))) void*)(smem + (LOFF)), 16, 0, 0)

#define LDA(SB, M) (*(const bf16x8*)(aLds + ((SB)*16384 + (M)*1024)))
#define LDB(SB, N) (*(const bf16x8*)(bLds + ((SB)*16384 + (N)*1024)))

#define STAGE_A(KT, SB) { const int t3_ = (KT) >> 4, ci3_ = ((KT) & 15) * 32;   \
    const size_t aB_ = (size_t)t3_ * (COUT * CIN) + ci3_;                       \
    GLDS(wt + aB_ + gA0, (SB) * 16384 + ldsd);                                  \
    GLDS(wt + aB_ + gA1, (SB) * 16384 + 8192 + ldsd); }

#define STAGE_B(KT, SB) { const int t3_ = (KT) >> 4, ci3_ = ((KT) & 15) * 32;   \
    const int bO_ = ((t3_ / 3) * WP + (t3_ % 3)) * CIN + ci3_;                  \
    GLDS(xpad + bO_ + gB0, 65536 + (SB) * 16384 + ldsd);                        \
    GLDS(xpad + bO_ + gB1, 65536 + (SB) * 16384 + 8192 + ldsd); }

#define BARRIER asm volatile("s_barrier" ::: "memory")
#define VM8 asm volatile("s_waitcnt vmcnt(8)" ::: "memory");
#define VM4 asm volatile("s_waitcnt vmcnt(4)" ::: "memory");
#define VM0 asm volatile("s_waitcnt vmcnt(0)" ::: "memory");
#define VMNONE

#define CCOL(N, BV) acc[0][N]=MM(ca0,BV,acc[0][N]); acc[1][N]=MM(ca1,BV,acc[1][N]); \
                    acc[2][N]=MM(ca2,BV,acc[2][N]); acc[3][N]=MM(ca3,BV,acc[3][N]);
#define XCOL(N, BV) acc[4][N]=MM(x4_,BV,acc[4][N]); acc[5][N]=MM(x5_,BV,acc[5][N]); \
                    acc[6][N]=MM(x6_,BV,acc[6][N]); acc[7][N]=MM(x7_,BV,acc[7][N]);

#define KTILE3(KK, SB, DOSTAGE, WAITER, DONEXT) {                               \
    bf16x8 x4_ = LDA(SB,4), x5_ = LDA(SB,5), x6_ = LDA(SB,6), x7_ = LDA(SB,7);  \
    if (DOSTAGE) { STAGE_A((KK)+3, ((SB)+3)&3); STAGE_B((KK)+3, ((SB)+3)&3); }  \
    __builtin_amdgcn_s_setprio(1);                                              \
    CCOL(0, cb0) CCOL(1, cb1) CCOL(2, cb2) CCOL(3, cb3)                         \
    __builtin_amdgcn_s_setprio(0);                                              \
    __builtin_amdgcn_sched_barrier(0);                                          \
    WAITER                                                                      \
    BARRIER;                                                                    \
    __builtin_amdgcn_sched_barrier(0);                                          \
    if (DONEXT) { const int nsb_ = ((SB)+1)&3;                                  \
        ca0 = LDA(nsb_,0); ca1 = LDA(nsb_,1);                                   \
        ca2 = LDA(nsb_,2); ca3 = LDA(nsb_,3);                                   \
        nb0_ = LDB(nsb_,0); nb1_ = LDB(nsb_,1);                                 \
        nb2_ = LDB(nsb_,2); nb3_ = LDB(nsb_,3);                                 \
    }                                                                           \
    __builtin_amdgcn_s_setprio(1);                                              \
    XCOL(0, cb0) XCOL(1, cb1) XCOL(2, cb2) XCOL(3, cb3)                         \
    __builtin_amdgcn_s_setprio(0);                                              \
    cb0 = nb0_; cb1 = nb1_; cb2 = nb2_; cb3 = nb3_;                             \
}

__global__ __launch_bounds__(512, 2) void k_conv(const __hip_bfloat16* __restrict__ wt,
                                                 const __hip_bfloat16* __restrict__ xpad,
                                                 const float* __restrict__ dfac,
                                                 float* __restrict__ out) {
    __shared__ __align__(16) char smem[131072];

    const int tid  = threadIdx.x;
    const int lane = tid & 63;
    const int wid  = tid >> 6;           // 8 waves
    const int wr   = wid >> 2;           // 0..1  (M: 128 rows each)
    const int wc   = wid & 3;            // 0..3  (N: 64 cols each)
    const int frow = lane & 15;
    const int fk   = lane >> 4;          // 0..3 (k-chunk of 8 bf16)

    // XCD-major decode: bid%8 = batch
    const int bid = blockIdx.x;
    const int bb  = bid & 7;
    const int pt  = (bid >> 3) & 15;
    const int ct  = bid >> 7;
    const int co0 = ct * 256;
    const int p0  = pt * 256;

    // ds_read bases: row*64B + swizzled chunk; swz(row) = (row>>1)&3 = (frow>>1)&3
    const int xr = (fk ^ ((frow >> 1) & 3)) * 16;
    const char* aLds = smem + (wr * 8192 + frow * 64 + xr);
    const char* bLds = smem + 65536 + (wc * 4096 + frow * 64 + xr);

    // staging: 16 rows x 64B per wave-instr, linear LDS; global source pre-swizzled
    const int ldsd = wid * 1024 + lane * 16;
    const int srow = wid * 16 + (lane >> 2);
    const int cg   = ((lane & 3) ^ ((lane >> 3) & 3)) * 8;
    const int gA0  = (co0 + srow) * CIN + cg;
    const int gA1  = (co0 + 128 + srow) * CIN + cg;
    const int pp0  = p0 + srow;
    const int pp1  = p0 + 128 + srow;
    const int gB0  = ((bb * HP + (pp0 >> 6)) * WP + (pp0 & 63)) * CIN + cg;
    const int gB1  = ((bb * HP + (pp1 >> 6)) * WP + (pp1 & 63)) * CIN + cg;

    f32x4 acc[8][4];
    #pragma unroll
    for (int m = 0; m < 8; ++m)
        #pragma unroll
        for (int n = 0; n < 4; ++n)
            acc[m][n] = (f32x4){0.f, 0.f, 0.f, 0.f};

    bf16x8 ca0, ca1, ca2, ca3, cb0, cb1, cb2, cb3, nb0_, nb1_, nb2_, nb3_;

    // prologue: stage K-tiles 0,1,2 into bufs 0,1,2
    STAGE_A(0, 0) STAGE_B(0, 0)
    STAGE_A(1, 1) STAGE_B(1, 1)
    STAGE_A(2, 2) STAGE_B(2, 2)
    VM8;       // tile 0 landed
    BARRIER;
    ca0 = LDA(0, 0); ca1 = LDA(0, 1); ca2 = LDA(0, 2); ca3 = LDA(0, 3);
    cb0 = LDB(0, 0); cb1 = LDB(0, 1); cb2 = LDB(0, 2); cb3 = LDB(0, 3);

    for (int k4 = 0; k4 < 140; k4 += 4) {
        KTILE3(k4 + 0, 0, 1, VM8, 1)
        KTILE3(k4 + 1, 1, 1, VM8, 1)
        KTILE3(k4 + 2, 2, 1, VM8, 1)
        KTILE3(k4 + 3, 3, 1, VM8, 1)
    }
    KTILE3(140, 0, 1, VM8, 1)     // stages tile 143; publishes 141
    KTILE3(141, 1, 0, VM4, 1)     // publishes 142
    KTILE3(142, 2, 0, VM0, 1)     // publishes 143
    KTILE3(143, 3, 0, VMNONE, 0)

    // epilogue: C/D mapping col(lane&15)=p, row=(lane>>4)*4+j = co; * dfac
    const float* dfb = dfac + bb * COUT;
    #pragma unroll
    for (int m = 0; m < 8; ++m) {
        int co = co0 + wr * 128 + m * 16 + fk * 4;
        float d0 = dfb[co + 0], d1 = dfb[co + 1], d2 = dfb[co + 2], d3 = dfb[co + 3];
        #pragma unroll
        for (int n = 0; n < 4; ++n) {
            int p = p0 + wc * 64 + n * 16 + frow;
            size_t ob = ((size_t)(bb * COUT + co)) * NP + p;
            out[ob]          = acc[m][n][0] * d0;
            out[ob + NP]     = acc[m][n][1] * d1;
            out[ob + 2 * NP] = acc[m][n][2] * d2;
            out[ob + 3 * NP] = acc[m][n][3] * d3;
        }
    }
}

// -----------------------------------------------------------------------------
extern "C" void kernel_launch(void* const* d_in, const int* in_sizes, int n_in,
                              void* d_out, int out_size, void* d_ws, size_t ws_size,
                              hipStream_t stream) {
    const float* x      = (const float*)d_in[0];
    const float* style  = (const float*)d_in[1];
    const float* weight = (const float*)d_in[2];
    const float* mod_w  = (const float*)d_in[3];
    const float* mod_b  = (const float*)d_in[4];
    float* out = (float*)d_out;

    char* ws = (char*)d_ws;
    const size_t M_OFF    = 0;                        // 8*512*4   = 16 KB
    const size_t DFAC_OFF = 16384;                    // 8*512*4   = 16 KB
    const size_t WT_OFF   = 32768;                    // 9*512*512*2 = 4.5 MB
    const size_t XPAD_OFF = WT_OFF + (size_t)9 * COUT * CIN * 2;

    float*          m_buf = (float*)(ws + M_OFF);
    float*          dfac  = (float*)(ws + DFAC_OFF);
    __hip_bfloat16* wt    = (__hip_bfloat16*)(ws + WT_OFF);
    __hip_bfloat16* xpad  = (__hip_bfloat16*)(ws + XPAD_OFF);

    k_mod<<<64, 256, 0, stream>>>(style, mod_w, mod_b, m_buf);
    k_prep<<<2560, 256, 0, stream>>>(x, weight, m_buf, xpad, wt, dfac);

    k_conv<<<256, 512, 0, stream>>>(wt, xpad, dfac, out);
}